// Round 4
// baseline (402.118 us; speedup 1.0000x reference)
//
#include <hip/hip_runtime.h>

// B=2, C=4, D=64, H=256, W=256
// out = sum_{interior, keep} ||omega_p - omega_t||_2 / sum(keep)
// keep = all 27 masks in 3x3x3 neighborhood == 1; omega = neighbor diffs of
// (pred - targ) ch1..3 (SCALES=10 cancels 2*DELTA=10).
//
// R3 post-mortem: __launch_bounds__(256) let the compiler target 8 waves/EU
// -> 64-VGPR cap -> loads re-sunk into consumption order -> ~2 loads in
// flight -> latency-serialized at 766 GB/s. Fix: __launch_bounds__(256, 2)
// (min 2 waves/EU = 2 blocks/CU, VGPR cap 256) so all 29 float4 loads can
// be register-resident and in flight simultaneously.

#define SD 65536LL      // d stride = H*W
#define SC 4194304LL    // channel stride = D*H*W

__global__ __launch_bounds__(256, 2) void vort_dense(
    const float* __restrict__ preds, const float* __restrict__ targs,
    const float* __restrict__ masks, double* __restrict__ acc)
{
    const int lane = threadIdx.x & 63;
    const int wv   = threadIdx.x >> 6;
    int blk = blockIdx.x;
    const int tile = blk & 63; blk >>= 6;       // 64 h-tiles of 4 rows
    const int d = blk % 62 + 1; blk /= 62;      // interior d 1..62
    const int b = blk;                          // 0..1
    const int h = 1 + tile * 4 + wv;            // one row per wave
    const int w0 = lane << 2;                   // 4 w per lane, full 256 row

    float norm = 0.0f, cnt = 0.0f;

    if (h <= 254) {   // wave-uniform guard (tile 63 waves 2,3 out of range)
        const long long mbase = (long long)b * SC + (long long)d * SD
                              + (long long)h * 256 + w0;
        const long long b1 = ((long long)(b * 4 + 1) * 64 + d) * SD
                           + (long long)h * 256 + w0;
        const long long b2 = b1 + SC;
        const long long b3 = b2 + SC;

        // ---- issue ALL loads first: 10 pred + 10 targ + 9 mask float4 ----
        long long voff[10];
        voff[0] = b1 - SD;  voff[1] = b1 + SD;   // u d-/d+
        voff[2] = b1 - 256; voff[3] = b1 + 256;  // u h-/h+
        voff[4] = b2 - SD;  voff[5] = b2 + SD;   // v d-/d+
        voff[6] = b2;                             // v center
        voff[7] = b3 - 256; voff[8] = b3 + 256;  // w h-/h+
        voff[9] = b3;                             // w center

        float4 P[10], T[10], Mv[9];
        #pragma unroll
        for (int i = 0; i < 10; ++i) P[i] = *(const float4*)(preds + voff[i]);
        #pragma unroll
        for (int i = 0; i < 10; ++i) T[i] = *(const float4*)(targs + voff[i]);
        #pragma unroll
        for (int r = 0; r < 9; ++r) {
            const int dd = r / 3 - 1, dh = r % 3 - 1;
            Mv[r] = *(const float4*)(masks + mbase + (long long)dd * SD
                                     + (long long)dh * 256);
        }

        // ---- consume: diffs, mask min, shuffle edges, per-cell norm ----
        float Df[10][4];
        #pragma unroll
        for (int i = 0; i < 10; ++i) {
            Df[i][0] = P[i].x - T[i].x; Df[i][1] = P[i].y - T[i].y;
            Df[i][2] = P[i].z - T[i].z; Df[i][3] = P[i].w - T[i].w;
        }
        float4 M = Mv[0];
        #pragma unroll
        for (int r = 1; r < 9; ++r) {
            M.x = fminf(M.x, Mv[r].x); M.y = fminf(M.y, Mv[r].y);
            M.z = fminf(M.z, Mv[r].z); M.w = fminf(M.w, Mv[r].w);
        }

        const float vL = __shfl_up(Df[6][3], 1, 64);
        const float vR = __shfl_down(Df[6][0], 1, 64);
        const float wL = __shfl_up(Df[9][3], 1, 64);
        const float wR = __shfl_down(Df[9][0], 1, 64);
        const float ML = __shfl_up(M.w, 1, 64);
        const float MR = __shfl_down(M.x, 1, 64);

        const float vv[6] = { vL, Df[6][0], Df[6][1], Df[6][2], Df[6][3], vR };
        const float ww[6] = { wL, Df[9][0], Df[9][1], Df[9][2], Df[9][3], wR };
        const float Mm[6] = { ML, M.x, M.y, M.z, M.w, MR };

        #pragma unroll
        for (int j = 0; j < 4; ++j) {
            const int wc = w0 + j;
            const float keepv = fminf(fminf(Mm[j], Mm[j + 1]), Mm[j + 2]);
            const bool valid = (wc >= 1) && (wc <= 254) && (keepv > 0.5f);
            const float wx = (Df[8][j] - Df[7][j]) - (Df[5][j] - Df[4][j]);
            const float wy = (Df[1][j] - Df[0][j]) - (ww[j + 2] - ww[j]);
            const float wz = (vv[j + 2] - vv[j]) - (Df[3][j] - Df[2][j]);
            const float n = sqrtf(wx * wx + wy * wy + wz * wz);
            norm += valid ? n : 0.0f;
            cnt  += valid ? 1.0f : 0.0f;
        }
    }

    // ---- reduction: wave shuffle -> LDS across 4 waves -> global atomic ----
    #pragma unroll
    for (int off = 32; off > 0; off >>= 1) {
        norm += __shfl_down(norm, off, 64);
        cnt  += __shfl_down(cnt,  off, 64);
    }
    __shared__ float ssum[4], scnt[4];
    if (lane == 0) { ssum[wv] = norm; scnt[wv] = cnt; }
    __syncthreads();
    if (threadIdx.x == 0) {
        const float s = ssum[0] + ssum[1] + ssum[2] + ssum[3];
        const float c = scnt[0] + scnt[1] + scnt[2] + scnt[3];
        atomicAdd(&acc[0], (double)s);
        atomicAdd(&acc[1], (double)c);
    }
}

__global__ void finalize_kernel(const double* __restrict__ acc, float* __restrict__ out)
{
    const double c = acc[1];
    out[0] = (c != 0.0) ? (float)(acc[0] / c) : 0.0f;
}

extern "C" void kernel_launch(void* const* d_in, const int* in_sizes, int n_in,
                              void* d_out, int out_size, void* d_ws, size_t ws_size,
                              hipStream_t stream)
{
    const float* preds = (const float*)d_in[0];
    const float* targs = (const float*)d_in[1];
    const float* masks = (const float*)d_in[2];
    float* out = (float*)d_out;
    double* acc = (double*)d_ws;

    hipMemsetAsync(d_ws, 0, 2 * sizeof(double), stream);

    const int nblocks = 2 * 62 * 64;   // (b, d-1, h-tile)
    vort_dense<<<nblocks, 256, 0, stream>>>(preds, targs, masks, acc);
    finalize_kernel<<<1, 1, 0, stream>>>(acc, out);
}

// Round 5
// 401.320 us; speedup vs baseline: 1.0020x; 1.0020x over previous
//
#include <hip/hip_runtime.h>

// B=2, C=4, D=64, H=256, W=256
// out = sum_{interior, keep} ||omega_p - omega_t||_2 / sum(keep)
// keep = all 27 masks in 3x3x3 neighborhood == 1; omega = neighbor diffs of
// (pred - targ) ch1..3 (SCALES=10 cancels 2*DELTA=10).
//
// R2-R4 post-mortem: identical 205us across three source structures; the
// MachineScheduler re-sinks every load to first use (VGPR 60/64/44) -> ~1
// load in flight/wave -> serialized at ~1650cyc congested latency.
// Fix: __builtin_amdgcn_sched_barrier(0) between the 29-float4 load cluster
// and all consumption — scheduler may not cross it, forcing all loads
// issued back-to-back and live (~170 VGPR, cap 256 via launch_bounds(256,2)).

#define SD 65536LL      // d stride = H*W
#define SC 4194304LL    // channel stride = D*H*W

__global__ __launch_bounds__(256, 2) void vort_dense(
    const float* __restrict__ preds, const float* __restrict__ targs,
    const float* __restrict__ masks, double* __restrict__ acc)
{
    const int lane = threadIdx.x & 63;
    const int wv   = threadIdx.x >> 6;
    int blk = blockIdx.x;
    const int tile = blk & 63; blk >>= 6;       // 64 h-tiles of 4 rows
    const int d = blk % 62 + 1; blk /= 62;      // interior d 1..62
    const int b = blk;                          // 0..1
    const int h = 1 + tile * 4 + wv;            // one row per wave
    const int w0 = lane << 2;                   // 4 w per lane, full 256 row

    float norm = 0.0f, cnt = 0.0f;

    if (h <= 254) {   // wave-uniform guard (tile 63 waves 2,3 out of range)
        const long long mbase = (long long)b * SC + (long long)d * SD
                              + (long long)h * 256 + w0;
        const long long b1 = ((long long)(b * 4 + 1) * 64 + d) * SD
                           + (long long)h * 256 + w0;
        const long long b2 = b1 + SC;
        const long long b3 = b2 + SC;

        // ---- issue ALL loads first: 10 pred + 10 targ + 9 mask float4 ----
        long long voff[10];
        voff[0] = b1 - SD;  voff[1] = b1 + SD;   // u d-/d+
        voff[2] = b1 - 256; voff[3] = b1 + 256;  // u h-/h+
        voff[4] = b2 - SD;  voff[5] = b2 + SD;   // v d-/d+
        voff[6] = b2;                             // v center
        voff[7] = b3 - 256; voff[8] = b3 + 256;  // w h-/h+
        voff[9] = b3;                             // w center

        float4 P[10], T[10], Mv[9];
        #pragma unroll
        for (int i = 0; i < 10; ++i) P[i] = *(const float4*)(preds + voff[i]);
        #pragma unroll
        for (int i = 0; i < 10; ++i) T[i] = *(const float4*)(targs + voff[i]);
        #pragma unroll
        for (int r = 0; r < 9; ++r) {
            const int dd = r / 3 - 1, dh = r % 3 - 1;
            Mv[r] = *(const float4*)(masks + mbase + (long long)dd * SD
                                     + (long long)dh * 256);
        }

        // Scheduler fence: no instruction may cross. Keeps all 29 loads
        // issued above this point with destinations live.
        __builtin_amdgcn_sched_barrier(0);

        // ---- consume: diffs, mask min, shuffle edges, per-cell norm ----
        float Df[10][4];
        #pragma unroll
        for (int i = 0; i < 10; ++i) {
            Df[i][0] = P[i].x - T[i].x; Df[i][1] = P[i].y - T[i].y;
            Df[i][2] = P[i].z - T[i].z; Df[i][3] = P[i].w - T[i].w;
        }
        float4 M = Mv[0];
        #pragma unroll
        for (int r = 1; r < 9; ++r) {
            M.x = fminf(M.x, Mv[r].x); M.y = fminf(M.y, Mv[r].y);
            M.z = fminf(M.z, Mv[r].z); M.w = fminf(M.w, Mv[r].w);
        }

        const float vL = __shfl_up(Df[6][3], 1, 64);
        const float vR = __shfl_down(Df[6][0], 1, 64);
        const float wL = __shfl_up(Df[9][3], 1, 64);
        const float wR = __shfl_down(Df[9][0], 1, 64);
        const float ML = __shfl_up(M.w, 1, 64);
        const float MR = __shfl_down(M.x, 1, 64);

        const float vv[6] = { vL, Df[6][0], Df[6][1], Df[6][2], Df[6][3], vR };
        const float ww[6] = { wL, Df[9][0], Df[9][1], Df[9][2], Df[9][3], wR };
        const float Mm[6] = { ML, M.x, M.y, M.z, M.w, MR };

        #pragma unroll
        for (int j = 0; j < 4; ++j) {
            const int wc = w0 + j;
            const float keepv = fminf(fminf(Mm[j], Mm[j + 1]), Mm[j + 2]);
            const bool valid = (wc >= 1) && (wc <= 254) && (keepv > 0.5f);
            const float wx = (Df[8][j] - Df[7][j]) - (Df[5][j] - Df[4][j]);
            const float wy = (Df[1][j] - Df[0][j]) - (ww[j + 2] - ww[j]);
            const float wz = (vv[j + 2] - vv[j]) - (Df[3][j] - Df[2][j]);
            const float n = sqrtf(wx * wx + wy * wy + wz * wz);
            norm += valid ? n : 0.0f;
            cnt  += valid ? 1.0f : 0.0f;
        }
    }

    // ---- reduction: wave shuffle -> LDS across 4 waves -> global atomic ----
    #pragma unroll
    for (int off = 32; off > 0; off >>= 1) {
        norm += __shfl_down(norm, off, 64);
        cnt  += __shfl_down(cnt,  off, 64);
    }
    __shared__ float ssum[4], scnt[4];
    if (lane == 0) { ssum[wv] = norm; scnt[wv] = cnt; }
    __syncthreads();
    if (threadIdx.x == 0) {
        const float s = ssum[0] + ssum[1] + ssum[2] + ssum[3];
        const float c = scnt[0] + scnt[1] + scnt[2] + scnt[3];
        atomicAdd(&acc[0], (double)s);
        atomicAdd(&acc[1], (double)c);
    }
}

__global__ void finalize_kernel(const double* __restrict__ acc, float* __restrict__ out)
{
    const double c = acc[1];
    out[0] = (c != 0.0) ? (float)(acc[0] / c) : 0.0f;
}

extern "C" void kernel_launch(void* const* d_in, const int* in_sizes, int n_in,
                              void* d_out, int out_size, void* d_ws, size_t ws_size,
                              hipStream_t stream)
{
    const float* preds = (const float*)d_in[0];
    const float* targs = (const float*)d_in[1];
    const float* masks = (const float*)d_in[2];
    float* out = (float*)d_out;
    double* acc = (double*)d_ws;

    hipMemsetAsync(d_ws, 0, 2 * sizeof(double), stream);

    const int nblocks = 2 * 62 * 64;   // (b, d-1, h-tile)
    vort_dense<<<nblocks, 256, 0, stream>>>(preds, targs, masks, acc);
    finalize_kernel<<<1, 1, 0, stream>>>(acc, out);
}